// Round 12
// baseline (239.313 us; speedup 1.0000x reference)
//
#include <hip/hip_runtime.h>
#include <hip/hip_bf16.h>
#include <stdint.h>
#include <stddef.h>

#define HIDDEN 1024
#define HEADS  16
#define HDIM   64
#define NBATCH 2
#define SEQ    2048
#define TOK    (NBATCH*SEQ)   // 4096

typedef __attribute__((ext_vector_type(8))) short bf16x8;
typedef __attribute__((ext_vector_type(4))) float f32x4;
typedef unsigned short bf16u;

__device__ __forceinline__ unsigned short f2bf(float f) {
  union { float f; unsigned int u; } c; c.f = f;
  unsigned int u = c.u;
  unsigned int r = (u + 0x7fffu + ((u >> 16) & 1u)) >> 16;  // RNE
  return (unsigned short)r;
}

__device__ __forceinline__ unsigned int pk2bf(float a, float b) {
  __hip_bfloat16 ba = __float2bfloat16(a), bb = __float2bfloat16(b);
  unsigned short ua, ub;
  __builtin_memcpy(&ua, &ba, 2);
  __builtin_memcpy(&ub, &bb, 2);
  return (unsigned int)ua | ((unsigned int)ub << 16);
}

// ---------------------------------------------------------------- convert
__global__ __launch_bounds__(256) void convert_kernel(
    const float* __restrict__ x,
    const float* __restrict__ wq, const float* __restrict__ wk,
    const float* __restrict__ wv, const float* __restrict__ wo,
    bf16u* __restrict__ xb, bf16u* __restrict__ wqkvb, bf16u* __restrict__ wob) {
  const int XG = TOK*HIDDEN/4;
  const int WG = HIDDEN*HIDDEN/4;
  int i = blockIdx.x*blockDim.x + threadIdx.x;
  const float* src; bf16u* dst; int off;
  if (i < XG)            { src = x;  dst = xb;                      off = i; }
  else if (i < XG+WG)    { src = wq; dst = wqkvb;                   off = i-XG; }
  else if (i < XG+2*WG)  { src = wk; dst = wqkvb +   HIDDEN*HIDDEN; off = i-XG-WG; }
  else if (i < XG+3*WG)  { src = wv; dst = wqkvb + 2*HIDDEN*HIDDEN; off = i-XG-2*WG; }
  else if (i < XG+4*WG)  { src = wo; dst = wob;                     off = i-XG-3*WG; }
  else return;
  float4 v = ((const float4*)src)[off];
  ushort4 o;
  o.x = f2bf(v.x); o.y = f2bf(v.y); o.z = f2bf(v.z); o.w = f2bf(v.w);
  *(ushort4*)&dst[(size_t)off*4] = o;
}

// ---------------------------------------------------------------- GEMM core
// 128x128 tile of A[M][K] * B[N][K]^T, K=1024, BK=32, double-buffered LDS,
// 2-phase pipeline (stage next BEFORE compute cur, raw s_barrier + vmcnt(0)
// only at iter end — __syncthreads would drain vmcnt before compute).
// As/Bs are [2][128*32] each (32 KB total).
__device__ __forceinline__ void gemm_core(const bf16u* __restrict__ Abase,
                                          const bf16u* __restrict__ Bbase,
                                          bf16u* As, bf16u* Bs,
                                          f32x4 (&acc)[4][4]) {
  const int K = HIDDEN;
  const int NT = K / 32;
  const int t = threadIdx.x;
  const int w = t >> 6, lane = t & 63;
  const int wm = (w >> 1) * 64, wn = (w & 1) * 64;
  const int row = lane & 15, kq = (lane >> 4) * 8;
  const int c0 = t, c1 = t + 256;
  const int rA0 = c0 >> 2, k80 = (c0 & 3) * 8;
  const int rA1 = c1 >> 2, k81 = (c1 & 3) * 8;

  auto stage = [&](int buf, int k0) {
    bf16u* a0 = As + buf*(128*32) + (size_t)(w*64)*8;
    bf16u* a1 = As + buf*(128*32) + (size_t)(256 + w*64)*8;
    bf16u* b0 = Bs + buf*(128*32) + (size_t)(w*64)*8;
    bf16u* b1 = Bs + buf*(128*32) + (size_t)(256 + w*64)*8;
    __builtin_amdgcn_global_load_lds(
        (const __attribute__((address_space(1))) void*)(Abase + (size_t)rA0*K + k0 + k80),
        (__attribute__((address_space(3))) void*)a0, 16, 0, 0);
    __builtin_amdgcn_global_load_lds(
        (const __attribute__((address_space(1))) void*)(Abase + (size_t)rA1*K + k0 + k81),
        (__attribute__((address_space(3))) void*)a1, 16, 0, 0);
    __builtin_amdgcn_global_load_lds(
        (const __attribute__((address_space(1))) void*)(Bbase + (size_t)rA0*K + k0 + k80),
        (__attribute__((address_space(3))) void*)b0, 16, 0, 0);
    __builtin_amdgcn_global_load_lds(
        (const __attribute__((address_space(1))) void*)(Bbase + (size_t)rA1*K + k0 + k81),
        (__attribute__((address_space(3))) void*)b1, 16, 0, 0);
  };

  stage(0, 0);
  asm volatile("s_waitcnt vmcnt(0)" ::: "memory");
  __builtin_amdgcn_s_barrier();

  for (int it = 0; it < NT; ++it) {
    const int cur = it & 1;
    if (it < NT-1) stage(cur ^ 1, (it + 1) * 32);   // issue BEFORE compute
    const bf16u* Ab = As + cur*(128*32);
    const bf16u* Bb = Bs + cur*(128*32);
    bf16x8 af[4], bf[4];
    #pragma unroll
    for (int mi = 0; mi < 4; mi++)
      af[mi] = *(const bf16x8*)&Ab[(wm + mi*16 + row)*32 + kq];
    #pragma unroll
    for (int ni = 0; ni < 4; ni++)
      bf[ni] = *(const bf16x8*)&Bb[(wn + ni*16 + row)*32 + kq];
    #pragma unroll
    for (int mi = 0; mi < 4; mi++)
      #pragma unroll
      for (int ni = 0; ni < 4; ni++)
        acc[mi][ni] = __builtin_amdgcn_mfma_f32_16x16x32_bf16(af[mi], bf[ni], acc[mi][ni], 0, 0, 0);
    if (it < NT-1) {
      asm volatile("s_waitcnt vmcnt(0)" ::: "memory");  // next tile staged
      __builtin_amdgcn_s_barrier();                     // reads of cur retired
    }
  }
}

// ---------------------------------------------------------------- QKV GEMM
__global__ __launch_bounds__(256) void qkv_kernel(
    const bf16u* __restrict__ xb, const bf16u* __restrict__ wqkvb,
    const float* __restrict__ bq, const float* __restrict__ bk, const float* __restrict__ bv,
    bf16u* __restrict__ qb, bf16u* __restrict__ kb, bf16u* __restrict__ vtb) {
  __shared__ bf16u As[2*128*32];
  __shared__ bf16u Bs[2*128*32];
  f32x4 z = {0.f,0.f,0.f,0.f};
  f32x4 acc[4][4];
  #pragma unroll
  for (int i = 0; i < 4; i++)
    #pragma unroll
    for (int j = 0; j < 4; j++) acc[i][j] = z;
  const int n0 = blockIdx.x * 128, m0 = blockIdx.y * 128;
  gemm_core(xb + (size_t)m0*HIDDEN, wqkvb + (size_t)n0*HIDDEN, As, Bs, acc);

  const int t = threadIdx.x, w = t >> 6, lane = t & 63;
  const int wm = (w >> 1) * 64, wn = (w & 1) * 64;
  #pragma unroll
  for (int mi = 0; mi < 4; mi++) {
    #pragma unroll
    for (int ni = 0; ni < 4; ni++) {
      const int col = n0 + wn + ni*16 + (lane & 15);
      const int which = col >> 10, c = col & 1023;
      const int head = c >> 6, d = c & 63;
      const float bias = (which == 0 ? bq : (which == 1 ? bk : bv))[c];
      #pragma unroll
      for (int j = 0; j < 4; j++) {
        const int rowm = m0 + wm + mi*16 + ((lane >> 4) * 4) + j;
        const int n = rowm >> 11, l = rowm & 2047;
        const bf16u hv = f2bf(acc[mi][ni][j] + bias);
        if (which == 0)
          qb[(((size_t)n*HEADS + head)*SEQ + l)*HDIM + d] = hv;
        else if (which == 1)
          kb[(((size_t)n*HEADS + head)*SEQ + l)*HDIM + d] = hv;
        else
          vtb[(((size_t)n*HEADS + head)*HDIM + d)*SEQ + l] = hv;
      }
    }
  }
}

// ---------------------------------------------------------------- attention
// QBLK=32 per wave (block = 128 q-rows, 4 waves). Swapped QK^T; each K/V
// fragment read feeds 2 MFMAs (qh=0,1). Denominator via ones-MFMA. Defer-max
// THR=0. K/V staged in LDS (linear dest + pre-swizzled source), 2-phase
// raw-barrier pipeline, end-of-iter vmcnt(0). LDS = 48KB.
__global__ __launch_bounds__(256) void attn_kernel(
    const bf16u* __restrict__ qb, const bf16u* __restrict__ kb,
    const bf16u* __restrict__ vtb, bf16u* __restrict__ ctxb) {
  __shared__ bf16u Ks[2][64*64];
  __shared__ bf16u Vs[2][64*64];
  __shared__ bf16u Pl[4][32*64];   // per-wave P[32][64], slot-swizzled
  const int t = threadIdx.x, w = t >> 6, lane = t & 63;
  const int row = lane & 15, hi = lane >> 4;
  const int qt = blockIdx.x, nh = blockIdx.y;
  const int n = nh >> 4, h = nh & 15;
  const bf16u* Qb = qb  + (size_t)nh * SEQ * HDIM;
  const bf16u* Kb = kb  + (size_t)nh * SEQ * HDIM;
  const bf16u* Vt = vtb + (size_t)nh * HDIM * SEQ;

  const int c0 = w*64 + lane, c1 = c0 + 256;
  const int r0 = c0 >> 3, e0 = ((c0 & 7) ^ (r0 & 7)) * 8;
  const int r1 = c1 >> 3, e1 = ((c1 & 7) ^ (r1 & 7)) * 8;

  const int qbase = qt*128 + w*32;
  bf16x8 aq[2][2];
  #pragma unroll
  for (int qh = 0; qh < 2; qh++)
    #pragma unroll
    for (int kc = 0; kc < 2; kc++)
      aq[qh][kc] = *(const bf16x8*)&Qb[(size_t)(qbase + qh*16 + row)*HDIM + kc*32 + hi*8];

  const short one_bf = (short)0x3F80;   // bf16 1.0
  const bf16x8 vone = {one_bf, one_bf, one_bf, one_bf, one_bf, one_bf, one_bf, one_bf};
  f32x4 z = {0.f,0.f,0.f,0.f};
  float mr[2] = {-1e30f, -1e30f};
  f32x4 ao[2][4] = {{z,z,z,z},{z,z,z,z}};
  f32x4 aden[2] = {z, z};
  bf16u* P = &Pl[w][0];

  auto stage = [&](int buf, int kv0) {
    __builtin_amdgcn_global_load_lds(
        (const __attribute__((address_space(1))) void*)(Kb + (size_t)(kv0 + r0)*HDIM + e0),
        (__attribute__((address_space(3))) void*)(&Ks[buf][(size_t)(w*64)*8]), 16, 0, 0);
    __builtin_amdgcn_global_load_lds(
        (const __attribute__((address_space(1))) void*)(Kb + (size_t)(kv0 + r1)*HDIM + e1),
        (__attribute__((address_space(3))) void*)(&Ks[buf][(size_t)(256 + w*64)*8]), 16, 0, 0);
    __builtin_amdgcn_global_load_lds(
        (const __attribute__((address_space(1))) void*)(Vt + (size_t)r0*SEQ + kv0 + e0),
        (__attribute__((address_space(3))) void*)(&Vs[buf][(size_t)(w*64)*8]), 16, 0, 0);
    __builtin_amdgcn_global_load_lds(
        (const __attribute__((address_space(1))) void*)(Vt + (size_t)r1*SEQ + kv0 + e1),
        (__attribute__((address_space(3))) void*)(&Vs[buf][(size_t)(256 + w*64)*8]), 16, 0, 0);
  };

  stage(0, 0);
  asm volatile("s_waitcnt vmcnt(0)" ::: "memory");
  __builtin_amdgcn_s_barrier();

  for (int it = 0; it < 32; ++it) {
    const int cur = it & 1;
    if (it < 31) stage(cur ^ 1, (it + 1) * 64);   // issue BEFORE compute

    // ---- QK^T (swapped): s[cb][qh][j] = S[kv=cb*16+hi*4+j][q=qh*16+row]
    f32x4 s[4][2];
    bf16x8 bk0[4], bk1[4];
    #pragma unroll
    for (int cb = 0; cb < 4; cb++) {
      const int kvr = cb*16 + row;
      const int sw = kvr & 7;
      bk0[cb] = *(const bf16x8*)&Ks[cur][kvr*64 + ((hi     ^ sw) * 8)];
      bk1[cb] = *(const bf16x8*)&Ks[cur][kvr*64 + (((4+hi) ^ sw) * 8)];
    }
    __builtin_amdgcn_s_setprio(1);
    #pragma unroll
    for (int cb = 0; cb < 4; cb++)
      #pragma unroll
      for (int qh = 0; qh < 2; qh++) {
        s[cb][qh] = __builtin_amdgcn_mfma_f32_16x16x32_bf16(bk0[cb], aq[qh][0], z, 0, 0, 0);
        s[cb][qh] = __builtin_amdgcn_mfma_f32_16x16x32_bf16(bk1[cb], aq[qh][1], s[cb][qh], 0, 0, 0);
      }
    __builtin_amdgcn_s_setprio(0);

    // ---- online softmax max per qh (in-lane 16 + 2 shuffles)
    float pm[2];
    #pragma unroll
    for (int qh = 0; qh < 2; qh++) {
      float m0 = s[0][qh][0];
      #pragma unroll
      for (int cb = 0; cb < 4; cb++)
        #pragma unroll
        for (int j = 0; j < 4; j++)
          m0 = fmaxf(m0, s[cb][qh][j]);
      m0 = fmaxf(m0, __shfl_xor(m0, 16));
      m0 = fmaxf(m0, __shfl_xor(m0, 32));
      pm[qh] = m0;
    }

    if (__any((pm[0] > mr[0]) || (pm[1] > mr[1]))) {  // defer-max THR=0
      #pragma unroll
      for (int qh = 0; qh < 2; qh++) {
        const float nm = fmaxf(mr[qh], pm[qh]);
        const float sc = __expf(mr[qh] - nm);
        mr[qh] = nm;
        float scj[4];
        #pragma unroll
        for (int j = 0; j < 4; j++)
          scj[j] = __shfl(sc, hi*4 + j);
        #pragma unroll
        for (int j = 0; j < 4; j++)
          aden[qh][j] *= scj[j];
        #pragma unroll
        for (int db = 0; db < 4; db++)
          #pragma unroll
          for (int j = 0; j < 4; j++)
            ao[qh][db][j] *= scj[j];
      }
    }

    // ---- exp + P pack -> per-wave LDS [q=32][kv=64], slot-swizzled
    #pragma unroll
    for (int qh = 0; qh < 2; qh++) {
      const int pr = qh*16 + row;
      #pragma unroll
      for (int cb = 0; cb < 4; cb++) {
        uint2 pk;
        pk.x = pk2bf(__expf(s[cb][qh][0] - mr[qh]), __expf(s[cb][qh][1] - mr[qh]));
        pk.y = pk2bf(__expf(s[cb][qh][2] - mr[qh]), __expf(s[cb][qh][3] - mr[qh]));
        const int slot = cb*2 + (hi >> 1);
        *(uint2*)&P[pr*64 + ((slot ^ (row & 7)) * 8) + (hi & 1)*4] = pk;
      }
    }
    asm volatile("s_waitcnt lgkmcnt(0)" ::: "memory");
    __builtin_amdgcn_sched_barrier(0);

    // ---- PV + denom from LDS
    bf16x8 ap[2][2], bv[2][4];
    #pragma unroll
    for (int qh = 0; qh < 2; qh++)
      #pragma unroll
      for (int ks = 0; ks < 2; ks++)
        ap[qh][ks] = *(const bf16x8*)&P[(qh*16 + row)*64 + (((ks*4+hi) ^ (row & 7)) * 8)];
    #pragma unroll
    for (int ks = 0; ks < 2; ks++)
      #pragma unroll
      for (int db = 0; db < 4; db++) {
        const int dr = db*16 + row;
        bv[ks][db] = *(const bf16x8*)&Vs[cur][dr*64 + (((ks*4+hi) ^ (dr & 7)) * 8)];
      }
    __builtin_amdgcn_s_setprio(1);
    #pragma unroll
    for (int ks = 0; ks < 2; ks++) {
      #pragma unroll
      for (int qh = 0; qh < 2; qh++) {
        #pragma unroll
        for (int db = 0; db < 4; db++)
          ao[qh][db] = __builtin_amdgcn_mfma_f32_16x16x32_bf16(ap[qh][ks], bv[ks][db], ao[qh][db], 0, 0, 0);
        aden[qh] = __builtin_amdgcn_mfma_f32_16x16x32_bf16(ap[qh][ks], vone, aden[qh], 0, 0, 0);
      }
    }
    __builtin_amdgcn_s_setprio(0);

    if (it < 31) asm volatile("s_waitcnt vmcnt(0)" ::: "memory");
    __builtin_amdgcn_s_barrier();
  }

  #pragma unroll
  for (int qh = 0; qh < 2; qh++) {
    float invj[4];
    #pragma unroll
    for (int j = 0; j < 4; j++)
      invj[j] = 1.0f / aden[qh][j];
    #pragma unroll
    for (int db = 0; db < 4; db++)
      #pragma unroll
      for (int j = 0; j < 4; j++) {
        const int l = qt*128 + w*32 + qh*16 + hi*4 + j;
        const int d = db*16 + row;
        ctxb[((size_t)n*SEQ + l)*HIDDEN + h*HDIM + d] = f2bf(ao[qh][db][j] * invj[j]);
      }
  }
}

// ---------------------------------------------------------------- output proj
__global__ __launch_bounds__(256) void oproj_kernel(
    const bf16u* __restrict__ ctxb, const bf16u* __restrict__ wob,
    const float* __restrict__ bo, float* __restrict__ out) {
  __shared__ bf16u As[2*128*32];
  __shared__ bf16u Bs[2*128*32];
  f32x4 z = {0.f,0.f,0.f,0.f};
  f32x4 acc[4][4];
  #pragma unroll
  for (int i = 0; i < 4; i++)
    #pragma unroll
    for (int j = 0; j < 4; j++) acc[i][j] = z;
  const int n0 = blockIdx.x * 128, m0 = blockIdx.y * 128;
  gemm_core(ctxb + (size_t)m0*HIDDEN, wob + (size_t)n0*HIDDEN, As, Bs, acc);

  const int t = threadIdx.x, w = t >> 6, lane = t & 63;
  const int wm = (w >> 1) * 64, wn = (w & 1) * 64;
  #pragma unroll
  for (int mi = 0; mi < 4; mi++) {
    #pragma unroll
    for (int ni = 0; ni < 4; ni++) {
      const int col = n0 + wn + ni*16 + (lane & 15);
      const float bias = bo[col];
      #pragma unroll
      for (int j = 0; j < 4; j++) {
        const int rowm = m0 + wm + mi*16 + ((lane >> 4)*4) + j;
        out[(size_t)rowm*HIDDEN + col] = acc[mi][ni][j] + bias;
      }
    }
  }
}

// ---------------------------------------------------------------- launch
extern "C" void kernel_launch(void* const* d_in, const int* in_sizes, int n_in,
                              void* d_out, int out_size, void* d_ws, size_t ws_size,
                              hipStream_t stream) {
  const float* x  = (const float*)d_in[0];
  const float* Wq = (const float*)d_in[1];
  const float* bq = (const float*)d_in[2];
  const float* Wk = (const float*)d_in[3];
  const float* bk = (const float*)d_in[4];
  const float* Wv = (const float*)d_in[5];
  const float* bv = (const float*)d_in[6];
  const float* Wo = (const float*)d_in[7];
  const float* bo = (const float*)d_in[8];
  float* out = (float*)d_out;

  bf16u* xb    = (bf16u*)d_ws;                         // [4096][1024]
  bf16u* wqkvb = xb    + (size_t)TOK*HIDDEN;           // [3072][1024]
  bf16u* wob   = wqkvb + (size_t)3*HIDDEN*HIDDEN;      // [1024][1024]
  bf16u* qb    = wob   + (size_t)HIDDEN*HIDDEN;        // [n][h][l][64]
  bf16u* kb    = qb    + (size_t)TOK*HIDDEN;           // [n][h][l][64]
  bf16u* vtb   = kb    + (size_t)TOK*HIDDEN;           // [n][h][64][l]
  bf16u* ctxb  = vtb   + (size_t)TOK*HIDDEN;           // [4096][1024]

  convert_kernel<<<8192, 256, 0, stream>>>(x, Wq, Wk, Wv, Wo, xb, wqkvb, wob);
  qkv_kernel<<<dim3(24, 32), 256, 0, stream>>>(xb, wqkvb, bq, bk, bv, qb, kb, vtb);
  attn_kernel<<<dim3(16, 32), 256, 0, stream>>>(qb, kb, vtb, ctxb);
  oproj_kernel<<<dim3(8, 32), 256, 0, stream>>>(ctxb, wob, bo, out);
}

// Round 15
// 226.773 us; speedup vs baseline: 1.0553x; 1.0553x over previous
//
#include <hip/hip_runtime.h>
#include <hip/hip_bf16.h>
#include <stdint.h>
#include <stddef.h>

#define HIDDEN 1024
#define HEADS  16
#define HDIM   64
#define NBATCH 2
#define SEQ    2048
#define TOK    (NBATCH*SEQ)   // 4096
#define LOG2E  1.44269504088896f

typedef __attribute__((ext_vector_type(8))) short bf16x8;
typedef __attribute__((ext_vector_type(4))) float f32x4;
typedef unsigned short bf16u;

__device__ __forceinline__ float fast_exp2(float x) {
  return __builtin_amdgcn_exp2f(x);   // bare v_exp_f32 (avoid glibc __exp2f macro clash)
}

__device__ __forceinline__ unsigned short f2bf(float f) {
  union { float f; unsigned int u; } c; c.f = f;
  unsigned int u = c.u;
  unsigned int r = (u + 0x7fffu + ((u >> 16) & 1u)) >> 16;  // RNE
  return (unsigned short)r;
}

__device__ __forceinline__ unsigned int pk2bf(float a, float b) {
  __hip_bfloat16 ba = __float2bfloat16(a), bb = __float2bfloat16(b);
  unsigned short ua, ub;
  __builtin_memcpy(&ua, &ba, 2);
  __builtin_memcpy(&ub, &bb, 2);
  return (unsigned int)ua | ((unsigned int)ub << 16);
}

// ---------------------------------------------------------------- convert
__global__ __launch_bounds__(256) void convert_kernel(
    const float* __restrict__ x,
    const float* __restrict__ wq, const float* __restrict__ wk,
    const float* __restrict__ wv, const float* __restrict__ wo,
    bf16u* __restrict__ xb, bf16u* __restrict__ wqkvb, bf16u* __restrict__ wob) {
  const int XG = TOK*HIDDEN/4;
  const int WG = HIDDEN*HIDDEN/4;
  int i = blockIdx.x*blockDim.x + threadIdx.x;
  const float* src; bf16u* dst; int off;
  if (i < XG)            { src = x;  dst = xb;                      off = i; }
  else if (i < XG+WG)    { src = wq; dst = wqkvb;                   off = i-XG; }
  else if (i < XG+2*WG)  { src = wk; dst = wqkvb +   HIDDEN*HIDDEN; off = i-XG-WG; }
  else if (i < XG+3*WG)  { src = wv; dst = wqkvb + 2*HIDDEN*HIDDEN; off = i-XG-2*WG; }
  else if (i < XG+4*WG)  { src = wo; dst = wob;                     off = i-XG-3*WG; }
  else return;
  float4 v = ((const float4*)src)[off];
  ushort4 o;
  o.x = f2bf(v.x); o.y = f2bf(v.y); o.z = f2bf(v.z); o.w = f2bf(v.w);
  *(ushort4*)&dst[(size_t)off*4] = o;
}

// ---------------------------------------------------------------- GEMM core
// (round-9 version: single-buffer + __syncthreads. Explicit dbuf measured
// neutral-to-negative in round 12 — implicit wave TLP already hides the drain.)
__device__ __forceinline__ void gemm_core(const bf16u* __restrict__ Abase,
                                          const bf16u* __restrict__ Bbase,
                                          bf16u* As, bf16u* Bs,
                                          f32x4 (&acc)[4][4]) {
  const int K = HIDDEN;
  const int t = threadIdx.x;
  const int w = t >> 6, lane = t & 63;
  const int wm = (w >> 1) * 64, wn = (w & 1) * 64;
  const int row = lane & 15, kq = (lane >> 4) * 8;
  const int c0 = t, c1 = t + 256;
  const int rA0 = c0 >> 2, k80 = (c0 & 3) * 8;
  const int rA1 = c1 >> 2, k81 = (c1 & 3) * 8;
  bf16u* ldsA0 = As + (size_t)(w*64)*8;
  bf16u* ldsA1 = As + (size_t)(256 + w*64)*8;
  bf16u* ldsB0 = Bs + (size_t)(w*64)*8;
  bf16u* ldsB1 = Bs + (size_t)(256 + w*64)*8;

  for (int k0 = 0; k0 < K; k0 += 32) {
    __builtin_amdgcn_global_load_lds(
        (const __attribute__((address_space(1))) void*)(Abase + (size_t)rA0*K + k0 + k80),
        (__attribute__((address_space(3))) void*)ldsA0, 16, 0, 0);
    __builtin_amdgcn_global_load_lds(
        (const __attribute__((address_space(1))) void*)(Abase + (size_t)rA1*K + k0 + k81),
        (__attribute__((address_space(3))) void*)ldsA1, 16, 0, 0);
    __builtin_amdgcn_global_load_lds(
        (const __attribute__((address_space(1))) void*)(Bbase + (size_t)rA0*K + k0 + k80),
        (__attribute__((address_space(3))) void*)ldsB0, 16, 0, 0);
    __builtin_amdgcn_global_load_lds(
        (const __attribute__((address_space(1))) void*)(Bbase + (size_t)rA1*K + k0 + k81),
        (__attribute__((address_space(3))) void*)ldsB1, 16, 0, 0);
    __syncthreads();
    bf16x8 af[4], bf[4];
    #pragma unroll
    for (int mi = 0; mi < 4; mi++)
      af[mi] = *(const bf16x8*)&As[(wm + mi*16 + row)*32 + kq];
    #pragma unroll
    for (int ni = 0; ni < 4; ni++)
      bf[ni] = *(const bf16x8*)&Bs[(wn + ni*16 + row)*32 + kq];
    #pragma unroll
    for (int mi = 0; mi < 4; mi++)
      #pragma unroll
      for (int ni = 0; ni < 4; ni++)
        acc[mi][ni] = __builtin_amdgcn_mfma_f32_16x16x32_bf16(af[mi], bf[ni], acc[mi][ni], 0, 0, 0);
    __syncthreads();
  }
}

// ---------------------------------------------------------------- QKV GEMM
// q columns pre-scaled by log2(e): attention's QK^T lands in the exp2 domain
// (one f32 multiply before the single bf16 round — no extra rounding step).
__global__ __launch_bounds__(256) void qkv_kernel(
    const bf16u* __restrict__ xb, const bf16u* __restrict__ wqkvb,
    const float* __restrict__ bq, const float* __restrict__ bk, const float* __restrict__ bv,
    bf16u* __restrict__ qb, bf16u* __restrict__ kb, bf16u* __restrict__ vtb) {
  __shared__ bf16u As[128*32];
  __shared__ bf16u Bs[128*32];
  f32x4 z = {0.f,0.f,0.f,0.f};
  f32x4 acc[4][4];
  #pragma unroll
  for (int i = 0; i < 4; i++)
    #pragma unroll
    for (int j = 0; j < 4; j++) acc[i][j] = z;
  const int n0 = blockIdx.x * 128, m0 = blockIdx.y * 128;
  gemm_core(xb + (size_t)m0*HIDDEN, wqkvb + (size_t)n0*HIDDEN, As, Bs, acc);

  const int t = threadIdx.x, w = t >> 6, lane = t & 63;
  const int wm = (w >> 1) * 64, wn = (w & 1) * 64;
  #pragma unroll
  for (int mi = 0; mi < 4; mi++) {
    #pragma unroll
    for (int ni = 0; ni < 4; ni++) {
      const int col = n0 + wn + ni*16 + (lane & 15);
      const int which = col >> 10, c = col & 1023;
      const int head = c >> 6, d = c & 63;
      const float bias = (which == 0 ? bq : (which == 1 ? bk : bv))[c];
      const float scale = (which == 0) ? LOG2E : 1.0f;
      #pragma unroll
      for (int j = 0; j < 4; j++) {
        const int rowm = m0 + wm + mi*16 + ((lane >> 4) * 4) + j;
        const int n = rowm >> 11, l = rowm & 2047;
        const bf16u hv = f2bf((acc[mi][ni][j] + bias) * scale);
        if (which == 0)
          qb[(((size_t)n*HEADS + head)*SEQ + l)*HDIM + d] = hv;
        else if (which == 1)
          kb[(((size_t)n*HEADS + head)*SEQ + l)*HDIM + d] = hv;
        else
          vtb[(((size_t)n*HEADS + head)*HDIM + d)*SEQ + l] = hv;
      }
    }
  }
}

// ---------------------------------------------------------------- attention
// QBLK=32 per wave. Swapped QK^T (scores already in log2 domain via scaled Q)
// -> softmax uses bare v_exp_f32 (fast_exp2), no per-element v_mul. Tree-max.
// Denominator via ones-MFMA. Defer-max THR=0. K/V staged in LDS (linear dest
// + pre-swizzled source), 2-phase raw-barrier pipeline. LDS = 48KB.
__global__ __launch_bounds__(256) void attn_kernel(
    const bf16u* __restrict__ qb, const bf16u* __restrict__ kb,
    const bf16u* __restrict__ vtb, bf16u* __restrict__ ctxb) {
  __shared__ bf16u Ks[2][64*64];
  __shared__ bf16u Vs[2][64*64];
  __shared__ bf16u Pl[4][32*64];   // per-wave P[32][64], slot-swizzled
  const int t = threadIdx.x, w = t >> 6, lane = t & 63;
  const int row = lane & 15, hi = lane >> 4;
  const int qt = blockIdx.x, nh = blockIdx.y;
  const int n = nh >> 4, h = nh & 15;
  const bf16u* Qb = qb  + (size_t)nh * SEQ * HDIM;
  const bf16u* Kb = kb  + (size_t)nh * SEQ * HDIM;
  const bf16u* Vt = vtb + (size_t)nh * HDIM * SEQ;

  const int c0 = w*64 + lane, c1 = c0 + 256;
  const int r0 = c0 >> 3, e0 = ((c0 & 7) ^ (r0 & 7)) * 8;
  const int r1 = c1 >> 3, e1 = ((c1 & 7) ^ (r1 & 7)) * 8;

  const int qbase = qt*128 + w*32;
  bf16x8 aq[2][2];
  #pragma unroll
  for (int qh = 0; qh < 2; qh++)
    #pragma unroll
    for (int kc = 0; kc < 2; kc++)
      aq[qh][kc] = *(const bf16x8*)&Qb[(size_t)(qbase + qh*16 + row)*HDIM + kc*32 + hi*8];

  const short one_bf = (short)0x3F80;   // bf16 1.0
  const bf16x8 vone = {one_bf, one_bf, one_bf, one_bf, one_bf, one_bf, one_bf, one_bf};
  f32x4 z = {0.f,0.f,0.f,0.f};
  float mr[2] = {-1e30f, -1e30f};
  f32x4 ao[2][4] = {{z,z,z,z},{z,z,z,z}};
  f32x4 aden[2] = {z, z};
  bf16u* P = &Pl[w][0];

  auto stage = [&](int buf, int kv0) {
    __builtin_amdgcn_global_load_lds(
        (const __attribute__((address_space(1))) void*)(Kb + (size_t)(kv0 + r0)*HDIM + e0),
        (__attribute__((address_space(3))) void*)(&Ks[buf][(size_t)(w*64)*8]), 16, 0, 0);
    __builtin_amdgcn_global_load_lds(
        (const __attribute__((address_space(1))) void*)(Kb + (size_t)(kv0 + r1)*HDIM + e1),
        (__attribute__((address_space(3))) void*)(&Ks[buf][(size_t)(256 + w*64)*8]), 16, 0, 0);
    __builtin_amdgcn_global_load_lds(
        (const __attribute__((address_space(1))) void*)(Vt + (size_t)r0*SEQ + kv0 + e0),
        (__attribute__((address_space(3))) void*)(&Vs[buf][(size_t)(w*64)*8]), 16, 0, 0);
    __builtin_amdgcn_global_load_lds(
        (const __attribute__((address_space(1))) void*)(Vt + (size_t)r1*SEQ + kv0 + e1),
        (__attribute__((address_space(3))) void*)(&Vs[buf][(size_t)(256 + w*64)*8]), 16, 0, 0);
  };

  stage(0, 0);
  asm volatile("s_waitcnt vmcnt(0)" ::: "memory");
  __builtin_amdgcn_s_barrier();

  for (int it = 0; it < 32; ++it) {
    const int cur = it & 1;
    if (it < 31) stage(cur ^ 1, (it + 1) * 64);   // issue BEFORE compute

    // ---- QK^T (swapped): s[cb][qh][j] = log2e*S[kv=cb*16+hi*4+j][q=qh*16+row]
    f32x4 s[4][2];
    bf16x8 bk0[4], bk1[4];
    #pragma unroll
    for (int cb = 0; cb < 4; cb++) {
      const int kvr = cb*16 + row;
      const int sw = kvr & 7;
      bk0[cb] = *(const bf16x8*)&Ks[cur][kvr*64 + ((hi     ^ sw) * 8)];
      bk1[cb] = *(const bf16x8*)&Ks[cur][kvr*64 + (((4+hi) ^ sw) * 8)];
    }
    __builtin_amdgcn_s_setprio(1);
    #pragma unroll
    for (int cb = 0; cb < 4; cb++)
      #pragma unroll
      for (int qh = 0; qh < 2; qh++) {
        s[cb][qh] = __builtin_amdgcn_mfma_f32_16x16x32_bf16(bk0[cb], aq[qh][0], z, 0, 0, 0);
        s[cb][qh] = __builtin_amdgcn_mfma_f32_16x16x32_bf16(bk1[cb], aq[qh][1], s[cb][qh], 0, 0, 0);
      }
    __builtin_amdgcn_s_setprio(0);

    // ---- online softmax max per qh (depth-4 tree + 2 shuffles)
    float pm[2];
    #pragma unroll
    for (int qh = 0; qh < 2; qh++) {
      float mcb[4];
      #pragma unroll
      for (int cb = 0; cb < 4; cb++)
        mcb[cb] = fmaxf(fmaxf(s[cb][qh][0], s[cb][qh][1]),
                        fmaxf(s[cb][qh][2], s[cb][qh][3]));
      float m0 = fmaxf(fmaxf(mcb[0], mcb[1]), fmaxf(mcb[2], mcb[3]));
      m0 = fmaxf(m0, __shfl_xor(m0, 16));
      m0 = fmaxf(m0, __shfl_xor(m0, 32));
      pm[qh] = m0;
    }

    if (__any((pm[0] > mr[0]) || (pm[1] > mr[1]))) {  // defer-max THR=0
      #pragma unroll
      for (int qh = 0; qh < 2; qh++) {
        const float nm = fmaxf(mr[qh], pm[qh]);
        const float sc = fast_exp2(mr[qh] - nm);      // log2 domain
        mr[qh] = nm;
        float scj[4];
        #pragma unroll
        for (int j = 0; j < 4; j++)
          scj[j] = __shfl(sc, hi*4 + j);
        #pragma unroll
        for (int j = 0; j < 4; j++)
          aden[qh][j] *= scj[j];
        #pragma unroll
        for (int db = 0; db < 4; db++)
          #pragma unroll
          for (int j = 0; j < 4; j++)
            ao[qh][db][j] *= scj[j];
      }
    }

    // ---- exp2 + P pack -> per-wave LDS [q=32][kv=64], slot-swizzled
    #pragma unroll
    for (int qh = 0; qh < 2; qh++) {
      const int pr = qh*16 + row;
      #pragma unroll
      for (int cb = 0; cb < 4; cb++) {
        uint2 pk;
        pk.x = pk2bf(fast_exp2(s[cb][qh][0] - mr[qh]), fast_exp2(s[cb][qh][1] - mr[qh]));
        pk.y = pk2bf(fast_exp2(s[cb][qh][2] - mr[qh]), fast_exp2(s[cb][qh][3] - mr[qh]));
        const int slot = cb*2 + (hi >> 1);
        *(uint2*)&P[pr*64 + ((slot ^ (row & 7)) * 8) + (hi & 1)*4] = pk;
      }
    }
    asm volatile("s_waitcnt lgkmcnt(0)" ::: "memory");
    __builtin_amdgcn_sched_barrier(0);

    // ---- PV + denom from LDS
    bf16x8 ap[2][2], bv[2][4];
    #pragma unroll
    for (int qh = 0; qh < 2; qh++)
      #pragma unroll
      for (int ks = 0; ks < 2; ks++)
        ap[qh][ks] = *(const bf16x8*)&P[(qh*16 + row)*64 + (((ks*4+hi) ^ (row & 7)) * 8)];
    #pragma unroll
    for (int ks = 0; ks < 2; ks++)
      #pragma unroll
      for (int db = 0; db < 4; db++) {
        const int dr = db*16 + row;
        bv[ks][db] = *(const bf16x8*)&Vs[cur][dr*64 + (((ks*4+hi) ^ (dr & 7)) * 8)];
      }
    __builtin_amdgcn_s_setprio(1);
    #pragma unroll
    for (int ks = 0; ks < 2; ks++) {
      #pragma unroll
      for (int qh = 0; qh < 2; qh++) {
        #pragma unroll
        for (int db = 0; db < 4; db++)
          ao[qh][db] = __builtin_amdgcn_mfma_f32_16x16x32_bf16(ap[qh][ks], bv[ks][db], ao[qh][db], 0, 0, 0);
        aden[qh] = __builtin_amdgcn_mfma_f32_16x16x32_bf16(ap[qh][ks], vone, aden[qh], 0, 0, 0);
      }
    }
    __builtin_amdgcn_s_setprio(0);

    if (it < 31) asm volatile("s_waitcnt vmcnt(0)" ::: "memory");
    __builtin_amdgcn_s_barrier();
  }

  #pragma unroll
  for (int qh = 0; qh < 2; qh++) {
    float invj[4];
    #pragma unroll
    for (int j = 0; j < 4; j++)
      invj[j] = 1.0f / aden[qh][j];
    #pragma unroll
    for (int db = 0; db < 4; db++)
      #pragma unroll
      for (int j = 0; j < 4; j++) {
        const int l = qt*128 + w*32 + qh*16 + hi*4 + j;
        const int d = db*16 + row;
        ctxb[((size_t)n*SEQ + l)*HIDDEN + h*HDIM + d] = f2bf(ao[qh][db][j] * invj[j]);
      }
  }
}

// ---------------------------------------------------------------- output proj
__global__ __launch_bounds__(256) void oproj_kernel(
    const bf16u* __restrict__ ctxb, const bf16u* __restrict__ wob,
    const float* __restrict__ bo, float* __restrict__ out) {
  __shared__ bf16u As[128*32];
  __shared__ bf16u Bs[128*32];
  f32x4 z = {0.f,0.f,0.f,0.f};
  f32x4 acc[4][4];
  #pragma unroll
  for (int i = 0; i < 4; i++)
    #pragma unroll
    for (int j = 0; j < 4; j++) acc[i][j] = z;
  const int n0 = blockIdx.x * 128, m0 = blockIdx.y * 128;
  gemm_core(ctxb + (size_t)m0*HIDDEN, wob + (size_t)n0*HIDDEN, As, Bs, acc);

  const int t = threadIdx.x, w = t >> 6, lane = t & 63;
  const int wm = (w >> 1) * 64, wn = (w & 1) * 64;
  #pragma unroll
  for (int mi = 0; mi < 4; mi++) {
    #pragma unroll
    for (int ni = 0; ni < 4; ni++) {
      const int col = n0 + wn + ni*16 + (lane & 15);
      const float bias = bo[col];
      #pragma unroll
      for (int j = 0; j < 4; j++) {
        const int rowm = m0 + wm + mi*16 + ((lane >> 4)*4) + j;
        out[(size_t)rowm*HIDDEN + col] = acc[mi][ni][j] + bias;
      }
    }
  }
}

// ---------------------------------------------------------------- launch
extern "C" void kernel_launch(void* const* d_in, const int* in_sizes, int n_in,
                              void* d_out, int out_size, void* d_ws, size_t ws_size,
                              hipStream_t stream) {
  const float* x  = (const float*)d_in[0];
  const float* Wq = (const float*)d_in[1];
  const float* bq = (const float*)d_in[2];
  const float* Wk = (const float*)d_in[3];
  const float* bk = (const float*)d_in[4];
  const float* Wv = (const float*)d_in[5];
  const float* bv = (const float*)d_in[6];
  const float* Wo = (const float*)d_in[7];
  const float* bo = (const float*)d_in[8];
  float* out = (float*)d_out;

  bf16u* xb    = (bf16u*)d_ws;                         // [4096][1024]
  bf16u* wqkvb = xb    + (size_t)TOK*HIDDEN;           // [3072][1024]
  bf16u* wob   = wqkvb + (size_t)3*HIDDEN*HIDDEN;      // [1024][1024]
  bf16u* qb    = wob   + (size_t)HIDDEN*HIDDEN;        // [n][h][l][64] (pre-scaled by log2e)
  bf16u* kb    = qb    + (size_t)TOK*HIDDEN;           // [n][h][l][64]
  bf16u* vtb   = kb    + (size_t)TOK*HIDDEN;           // [n][h][64][l]
  bf16u* ctxb  = vtb   + (size_t)TOK*HIDDEN;           // [4096][1024]

  convert_kernel<<<8192, 256, 0, stream>>>(x, Wq, Wk, Wv, Wo, xb, wqkvb, wob);
  qkv_kernel<<<dim3(24, 32), 256, 0, stream>>>(xb, wqkvb, bq, bk, bv, qb, kb, vtb);
  attn_kernel<<<dim3(16, 32), 256, 0, stream>>>(qb, kb, vtb, ctxb);
  oproj_kernel<<<dim3(8, 32), 256, 0, stream>>>(ctxb, wob, bo, out);
}